// Round 15
// baseline (138.104 us; speedup 1.0000x reference)
//
#include <hip/hip_runtime.h>

// Chamfer (bidirectional 1-NN mean of squared distances), two [16384,3] fp32 clouds.
// Round-15: MEASUREMENT ROUND. 8 structural nulls (R7-R14, all ~44-47us total,
// including a 2x MFMA-work cut in R14) mean the ~30us attribution to chamfer_mfma
// (inferred by subtraction; kernel never visible in top-5 under the 39us harness
// poison fills) is the suspect. Exploit min-idempotence: repeat the inner sweep
// REP=8 times with a memory clobber (blocks LICM/CSE collapsing reps) -> result
// identical, inner-loop time x8:
//   (1) P = (total - 46.6)/7 measures the true per-pass time,
//   (2) the now-long kernel enters top-5 -> first direct MfmaUtil/VALUBusy/VGPR/
//       Occupancy read.
// Branch (a) total ~85-100 -> kernel ~6-8us, floor is overhead/prep/reduce.
// Branch (b) total ~230-280 -> kernel ~30us, counters say which pipe.
// Compute identical to R14 (verified absmax 0.0).

typedef _Float16 half8 __attribute__((ext_vector_type(8)));
typedef float floatx16 __attribute__((ext_vector_type(16)));

#define NPTS 16384
#define BLOCK 256
#define WAVES 4
#define TILE 32
#define ROWSW (2 * TILE)              // 64 A-rows per wave (2 fragments)
#define APB (WAVES * ROWSW)           // 256 A-points per block
#define NBSPLIT 16
#define BSWEEP (NPTS / NBSPLIT)       // 1024 B-points per block
#define NTILES (BSWEEP / TILE)        // 32 B-tiles per block
#define REP 8                         // idempotent re-sweeps (measurement)

union H8 { _Float16 h[8]; uint4 u; };

__global__ __launch_bounds__(256) void prep_kernel(
    const float* __restrict__ P0, const float* __restrict__ P1,
    uint4* __restrict__ Ap, uint4* __restrict__ Bp,
    unsigned* __restrict__ dmin_all)
{
    const int i = blockIdx.x * 256 + threadIdx.x;      // 0..2*NPTS-1
    dmin_all[i] = 0x7F7F7F7Fu;                         // 3.39e38 > any real distance

    const bool isA = (i < NPTS);
    const float* P = isA ? P0 : P1;
    const int k = isA ? i : i - NPTS;
    const float x = P[k * 3 + 0], y = P[k * 3 + 1], z = P[k * 3 + 2];
    const float q2 = x * x + y * y + z * z;

    const _Float16 xh = (_Float16)x; const float xl = x - (float)xh;
    const _Float16 yh = (_Float16)y; const float yl = y - (float)yh;
    const _Float16 zh = (_Float16)z; const float zl = z - (float)zh;
    const _Float16 qh = (_Float16)q2; const float ql = q2 - (float)qh;
    const _Float16 one = (_Float16)1.0f, zero = (_Float16)0.0f;

    if (isA) {
        H8 a0, a1;
        a0.h[0] = (_Float16)(-2.0f * (float)xh);
        a0.h[1] = (_Float16)(-2.0f * (float)yh);
        a0.h[2] = (_Float16)(-2.0f * (float)zh);
        a0.h[3] = a0.h[0]; a0.h[4] = a0.h[1]; a0.h[5] = a0.h[2];
        a0.h[6] = (_Float16)(-2.0f * xl);
        a0.h[7] = (_Float16)(-2.0f * yl);
        a1.h[0] = (_Float16)(-2.0f * zl);
        a1.h[1] = qh; a1.h[2] = (_Float16)ql;
        a1.h[3] = one; a1.h[4] = one;
        a1.h[5] = zero; a1.h[6] = zero; a1.h[7] = zero;
        Ap[(size_t)k * 2 + 0] = a0.u; Ap[(size_t)k * 2 + 1] = a1.u;
    } else {
        H8 b0, b1;
        b0.h[0] = xh; b0.h[1] = yh; b0.h[2] = zh;
        b0.h[3] = (_Float16)xl; b0.h[4] = (_Float16)yl; b0.h[5] = (_Float16)zl;
        b0.h[6] = xh; b0.h[7] = yh;
        b1.h[0] = zh; b1.h[1] = one; b1.h[2] = one;
        b1.h[3] = qh; b1.h[4] = (_Float16)ql;
        b1.h[5] = zero; b1.h[6] = zero; b1.h[7] = zero;
        Bp[(size_t)k * 2 + 0] = b0.u; Bp[(size_t)k * 2 + 1] = b1.u;
    }
}

#define MF(afx, bf) __builtin_amdgcn_mfma_f32_32x32x16_f16((afx), (bf), ZC, 0, 0, 0)

__global__ __launch_bounds__(BLOCK, 4) void chamfer_mfma(
    const uint4* __restrict__ Ap, const uint4* __restrict__ Bp,
    unsigned* __restrict__ dmin_all)
{
    __shared__ unsigned scmin[BSWEEP];   // block-level col-min accumulator (4 KB)

    const int tid  = threadIdx.x;
    const int lane = tid & 63;
    const int wid  = tid >> 6;
    const int half = lane >> 5;
    const int lj   = lane & 31;

    for (int i = tid; i < BSWEEP; i += BLOCK) scmin[i] = 0x7F7F7F7Fu;
    __syncthreads();

    const int arow0 = blockIdx.x * APB + wid * ROWSW;

    const half8 af0 = *reinterpret_cast<const half8*>(
        &Ap[((size_t)(arow0 + lj)) * 2 + half]);
    const half8 af1 = *reinterpret_cast<const half8*>(
        &Ap[((size_t)(arow0 + 32 + lj)) * 2 + half]);

    const floatx16 ZC = (floatx16)(0.0f);

    float rmin0[16], rmin1[16];
#pragma unroll
    for (int r = 0; r < 16; ++r) { rmin0[r] = 3.0e38f; rmin1[r] = 3.0e38f; }

    const int bbase = blockIdx.y * BSWEEP;
    const uint4* Bc = Bp + (size_t)bbase * 2;

    // MEASUREMENT: REP idempotent sweeps. min(min(x,y),y)=min(x,y), and scmin
    // atomics are idempotent too -> result identical to REP=1. The memory
    // clobber prevents the compiler hoisting loads / CSE-ing reps away.
#pragma unroll 1
    for (int rep = 0; rep < REP; ++rep) {
        asm volatile("" ::: "memory");
#pragma unroll 2
        for (int t = 0; t < NTILES; ++t) {
            const half8 bf = *reinterpret_cast<const half8*>(
                &Bc[(size_t)(t * TILE + lj) * 2 + half]);
            const floatx16 dA = MF(af0, bf);
            const floatx16 dB = MF(af1, bf);
#pragma unroll
            for (int r = 0; r < 16; ++r) {
                rmin0[r] = fminf(dA[r], rmin0[r]);
                rmin1[r] = fminf(dB[r], rmin1[r]);
            }
            float c = fminf(dA[0], dB[0]);
#pragma unroll
            for (int r = 1; r < 16; ++r) c = fminf(fminf(dA[r], dB[r]), c);
            c = fminf(c, __shfl_xor(c, 32, 64));
            if (lane < 32)
                atomicMin(&scmin[t * TILE + lj], __float_as_uint(fmaxf(c, 0.0f)));
        }
    }

#pragma unroll
    for (int r = 0; r < 16; ++r) {
        float v0 = rmin0[r];
        v0 = fminf(v0, __shfl_xor(v0, 1, 32));
        v0 = fminf(v0, __shfl_xor(v0, 2, 32));
        v0 = fminf(v0, __shfl_xor(v0, 4, 32));
        v0 = fminf(v0, __shfl_xor(v0, 8, 32));
        v0 = fminf(v0, __shfl_xor(v0, 16, 32));
        rmin0[r] = v0;
        float v1 = rmin1[r];
        v1 = fminf(v1, __shfl_xor(v1, 1, 32));
        v1 = fminf(v1, __shfl_xor(v1, 2, 32));
        v1 = fminf(v1, __shfl_xor(v1, 4, 32));
        v1 = fminf(v1, __shfl_xor(v1, 8, 32));
        v1 = fminf(v1, __shfl_xor(v1, 16, 32));
        rmin1[r] = v1;
    }
    if (lj == 0) {
#pragma unroll
        for (int r = 0; r < 16; ++r) {
            const int row = (r & 3) + 8 * (r >> 2) + 4 * half;
            atomicMin(&dmin_all[arow0 + row],
                      __float_as_uint(fmaxf(rmin0[r], 0.0f)));
            atomicMin(&dmin_all[arow0 + 32 + row],
                      __float_as_uint(fmaxf(rmin1[r], 0.0f)));
        }
    }

    __syncthreads();
    for (int i = tid; i < BSWEEP; i += BLOCK)
        atomicMin(&dmin_all[NPTS + bbase + i], scmin[i]);
}

__global__ __launch_bounds__(1024) void chamfer_reduce_kernel(
    const unsigned* __restrict__ dmin_all, float* __restrict__ out)
{
    __shared__ double sdata[1024];
    double s = 0.0;
    for (int i = threadIdx.x; i < 2 * NPTS; i += 1024)
        s += (double)__uint_as_float(dmin_all[i]);
    sdata[threadIdx.x] = s;
    __syncthreads();
    for (int off = 512; off > 0; off >>= 1) {
        if (threadIdx.x < off) sdata[threadIdx.x] += sdata[threadIdx.x + off];
        __syncthreads();
    }
    if (threadIdx.x == 0) out[0] = (float)(sdata[0] / (double)NPTS);
}

extern "C" void kernel_launch(void* const* d_in, const int* in_sizes, int n_in,
                              void* d_out, int out_size, void* d_ws, size_t ws_size,
                              hipStream_t stream)
{
    const float* P0 = (const float*)d_in[0];
    const float* P1 = (const float*)d_in[1];
    float* out = (float*)d_out;

    unsigned* dmin = (unsigned*)d_ws;                                     // 128 KB
    uint4* Ap = (uint4*)((char*)d_ws + 2 * NPTS * sizeof(unsigned));      // 512 KB
    uint4* Bp = Ap + (size_t)NPTS * 2;                                    // 512 KB

    prep_kernel<<<(2 * NPTS) / 256, 256, 0, stream>>>(P0, P1, Ap, Bp, dmin);

    dim3 grid(NPTS / APB, NBSPLIT);   // 64 x 16 = 1024 blocks, 4 blocks/CU
    chamfer_mfma<<<grid, BLOCK, 0, stream>>>(Ap, Bp, dmin);

    chamfer_reduce_kernel<<<1, 1024, 0, stream>>>(dmin, out);
}

// Round 16
// 41.833 us; speedup vs baseline: 3.3013x; 3.3013x over previous
//
#include <hip/hip_runtime.h>

// Chamfer (bidirectional 1-NN mean of squared distances), two [16384,3] fp32 clouds.
// Round-16: R15 measurement isolated the cost: per-sweep P~13us + in-kernel fixed
// F~20us. F = the 1M contended global atomicMin col-merge (64 x-blocks RMW each of
// 16K cols). Fix: blocks STORE col-min partials to a private slab colpart[bx][col]
// (plain coalesced stores, 4MB, no contention); a 64-block merge kernel min-reduces
// the 64 partials per col and folds in the row-side dmin into per-block double
// sums; a tiny final kernel sums 64 doubles. Inner loop byte-identical to R14
// (verified absmax 0.0, VGPR=64). Row atomics kept (8K only).
//
// MFMA formulation (one v_mfma_f32_32x32x16_f16 per 32x32 distance tile):
//   x = xh + xl (split fp16). K slots:
//     0..2 A=-2a_hi B=b_hi | 3..5 A=-2a_hi B=b_lo | 6..8 A=-2a_lo B=b_hi
//     9,10 A={a2_hi,a2_lo} B={1,1} | 11,12 A={1,1} B={b2_hi,b2_lo} | 13..15 zero
//   => D[i][j] = a2 + b2 - 2 a.b + O(3e-3), fp32 accumulators.
// C/D layout (verified): col=lane&31, row=(reg&3)+8*(reg>>2)+4*(lane>>5).

typedef _Float16 half8 __attribute__((ext_vector_type(8)));
typedef float floatx16 __attribute__((ext_vector_type(16)));

#define NPTS 16384
#define BLOCK 256
#define WAVES 4
#define TILE 32
#define ROWSW (2 * TILE)              // 64 A-rows per wave (2 fragments)
#define APB (WAVES * ROWSW)           // 256 A-points per block
#define NXB (NPTS / APB)              // 64 x-blocks (= col-partial slabs)
#define NBSPLIT 16
#define BSWEEP (NPTS / NBSPLIT)       // 1024 B-points per block
#define NTILES (BSWEEP / TILE)        // 32 B-tiles per block

union H8 { _Float16 h[8]; uint4 u; };

// P0 -> A-frags, P1 -> B-frags (32 B/point); init row-min array (NPTS u32).
__global__ __launch_bounds__(256) void prep_kernel(
    const float* __restrict__ P0, const float* __restrict__ P1,
    uint4* __restrict__ Ap, uint4* __restrict__ Bp,
    unsigned* __restrict__ dmin_row)
{
    const int i = blockIdx.x * 256 + threadIdx.x;      // 0..2*NPTS-1
    const bool isA = (i < NPTS);
    if (isA) dmin_row[i] = 0x7F7F7F7Fu;                // 3.39e38 > any real distance

    const float* P = isA ? P0 : P1;
    const int k = isA ? i : i - NPTS;
    const float x = P[k * 3 + 0], y = P[k * 3 + 1], z = P[k * 3 + 2];
    const float q2 = x * x + y * y + z * z;

    const _Float16 xh = (_Float16)x; const float xl = x - (float)xh;
    const _Float16 yh = (_Float16)y; const float yl = y - (float)yh;
    const _Float16 zh = (_Float16)z; const float zl = z - (float)zh;
    const _Float16 qh = (_Float16)q2; const float ql = q2 - (float)qh;
    const _Float16 one = (_Float16)1.0f, zero = (_Float16)0.0f;

    if (isA) {
        H8 a0, a1;
        a0.h[0] = (_Float16)(-2.0f * (float)xh);
        a0.h[1] = (_Float16)(-2.0f * (float)yh);
        a0.h[2] = (_Float16)(-2.0f * (float)zh);
        a0.h[3] = a0.h[0]; a0.h[4] = a0.h[1]; a0.h[5] = a0.h[2];
        a0.h[6] = (_Float16)(-2.0f * xl);
        a0.h[7] = (_Float16)(-2.0f * yl);
        a1.h[0] = (_Float16)(-2.0f * zl);
        a1.h[1] = qh; a1.h[2] = (_Float16)ql;
        a1.h[3] = one; a1.h[4] = one;
        a1.h[5] = zero; a1.h[6] = zero; a1.h[7] = zero;
        Ap[(size_t)k * 2 + 0] = a0.u; Ap[(size_t)k * 2 + 1] = a1.u;
    } else {
        H8 b0, b1;
        b0.h[0] = xh; b0.h[1] = yh; b0.h[2] = zh;
        b0.h[3] = (_Float16)xl; b0.h[4] = (_Float16)yl; b0.h[5] = (_Float16)zl;
        b0.h[6] = xh; b0.h[7] = yh;
        b1.h[0] = zh; b1.h[1] = one; b1.h[2] = one;
        b1.h[3] = qh; b1.h[4] = (_Float16)ql;
        b1.h[5] = zero; b1.h[6] = zero; b1.h[7] = zero;
        Bp[(size_t)k * 2 + 0] = b0.u; Bp[(size_t)k * 2 + 1] = b1.u;
    }
}

#define MF(afx, bf) __builtin_amdgcn_mfma_f32_32x32x16_f16((afx), (bf), ZC, 0, 0, 0)

__global__ __launch_bounds__(BLOCK, 4) void chamfer_mfma(
    const uint4* __restrict__ Ap, const uint4* __restrict__ Bp,
    unsigned* __restrict__ dmin_row, unsigned* __restrict__ colpart)
{
    __shared__ unsigned scmin[BSWEEP];   // block-level col-min accumulator (4 KB)

    const int tid  = threadIdx.x;
    const int lane = tid & 63;
    const int wid  = tid >> 6;
    const int half = lane >> 5;
    const int lj   = lane & 31;

    for (int i = tid; i < BSWEEP; i += BLOCK) scmin[i] = 0x7F7F7F7Fu;
    __syncthreads();

    const int arow0 = blockIdx.x * APB + wid * ROWSW;

    const half8 af0 = *reinterpret_cast<const half8*>(
        &Ap[((size_t)(arow0 + lj)) * 2 + half]);
    const half8 af1 = *reinterpret_cast<const half8*>(
        &Ap[((size_t)(arow0 + 32 + lj)) * 2 + half]);

    const floatx16 ZC = (floatx16)(0.0f);

    float rmin0[16], rmin1[16];
#pragma unroll
    for (int r = 0; r < 16; ++r) { rmin0[r] = 3.0e38f; rmin1[r] = 3.0e38f; }

    const int bbase = blockIdx.y * BSWEEP;
    const uint4* Bc = Bp + (size_t)bbase * 2;

    // Inner loop identical to R14 (verified): per B-tile, 2 MFMAs, row mins into
    // registers, col tree + cross-half shuffle + LDS atomic. B direct from L2.
#pragma unroll 2
    for (int t = 0; t < NTILES; ++t) {
        const half8 bf = *reinterpret_cast<const half8*>(
            &Bc[(size_t)(t * TILE + lj) * 2 + half]);
        const floatx16 dA = MF(af0, bf);
        const floatx16 dB = MF(af1, bf);
#pragma unroll
        for (int r = 0; r < 16; ++r) {
            rmin0[r] = fminf(dA[r], rmin0[r]);
            rmin1[r] = fminf(dB[r], rmin1[r]);
        }
        float c = fminf(dA[0], dB[0]);
#pragma unroll
        for (int r = 1; r < 16; ++r) c = fminf(fminf(dA[r], dB[r]), c);
        c = fminf(c, __shfl_xor(c, 32, 64));
        if (lane < 32)
            atomicMin(&scmin[t * TILE + lj], __float_as_uint(fmaxf(c, 0.0f)));
    }

    // Row-side: butterfly + global atomicMin (8K atomics total, cheap).
#pragma unroll
    for (int r = 0; r < 16; ++r) {
        float v0 = rmin0[r];
        v0 = fminf(v0, __shfl_xor(v0, 1, 32));
        v0 = fminf(v0, __shfl_xor(v0, 2, 32));
        v0 = fminf(v0, __shfl_xor(v0, 4, 32));
        v0 = fminf(v0, __shfl_xor(v0, 8, 32));
        v0 = fminf(v0, __shfl_xor(v0, 16, 32));
        rmin0[r] = v0;
        float v1 = rmin1[r];
        v1 = fminf(v1, __shfl_xor(v1, 1, 32));
        v1 = fminf(v1, __shfl_xor(v1, 2, 32));
        v1 = fminf(v1, __shfl_xor(v1, 4, 32));
        v1 = fminf(v1, __shfl_xor(v1, 8, 32));
        v1 = fminf(v1, __shfl_xor(v1, 16, 32));
        rmin1[r] = v1;
    }
    if (lj == 0) {
#pragma unroll
        for (int r = 0; r < 16; ++r) {
            const int row = (r & 3) + 8 * (r >> 2) + 4 * half;
            atomicMin(&dmin_row[arow0 + row],
                      __float_as_uint(fmaxf(rmin0[r], 0.0f)));
            atomicMin(&dmin_row[arow0 + 32 + row],
                      __float_as_uint(fmaxf(rmin1[r], 0.0f)));
        }
    }

    // Col-side: plain coalesced stores to this x-block's private partial slab.
    __syncthreads();
    unsigned* dst = colpart + (size_t)blockIdx.x * NPTS + bbase;
    for (int i = tid; i < BSWEEP; i += BLOCK) dst[i] = scmin[i];
}

// Per-column min over the 64 x-block partials (coalesced, contention-free),
// fold in the row-side mins, block-reduce to 64 double partial sums.
__global__ __launch_bounds__(256) void merge_kernel(
    const unsigned* __restrict__ colpart, const unsigned* __restrict__ dmin_row,
    double* __restrict__ part)
{
    const int tid = threadIdx.x;
    const int c = blockIdx.x * 256 + tid;   // one column per thread
    unsigned m = 0x7F7F7F7Fu;
#pragma unroll
    for (int p = 0; p < NXB; ++p)
        m = min(m, colpart[(size_t)p * NPTS + c]);
    double s = (double)__uint_as_float(m) + (double)__uint_as_float(dmin_row[c]);

    __shared__ double sd[256];
    sd[tid] = s;
    __syncthreads();
    for (int off = 128; off > 0; off >>= 1) {
        if (tid < off) sd[tid] += sd[tid + off];
        __syncthreads();
    }
    if (tid == 0) part[blockIdx.x] = sd[0];
}

__global__ __launch_bounds__(64) void final_kernel(
    const double* __restrict__ part, float* __restrict__ out)
{
    __shared__ double sd[64];
    sd[threadIdx.x] = part[threadIdx.x];
    __syncthreads();
    for (int off = 32; off > 0; off >>= 1) {
        if (threadIdx.x < off) sd[threadIdx.x] += sd[threadIdx.x + off];
        __syncthreads();
    }
    // mean(dist0) + mean(dist1) = (sum_rows + sum_cols) / NPTS
    if (threadIdx.x == 0) out[0] = (float)(sd[0] / (double)NPTS);
}

extern "C" void kernel_launch(void* const* d_in, const int* in_sizes, int n_in,
                              void* d_out, int out_size, void* d_ws, size_t ws_size,
                              hipStream_t stream)
{
    const float* P0 = (const float*)d_in[0];
    const float* P1 = (const float*)d_in[1];
    float* out = (float*)d_out;

    char* ws = (char*)d_ws;
    unsigned* dmin_row = (unsigned*)ws;                       // 64 KB
    uint4* Ap = (uint4*)(ws + 64 * 1024);                     // 512 KB
    uint4* Bp = (uint4*)(ws + 576 * 1024);                    // 512 KB
    unsigned* colpart = (unsigned*)(ws + 1088 * 1024);        // 64*16384*4 = 4 MB
    double* part = (double*)(ws + 1088 * 1024 + 4 * 1024 * 1024);  // 512 B

    prep_kernel<<<(2 * NPTS) / 256, 256, 0, stream>>>(P0, P1, Ap, Bp, dmin_row);

    dim3 grid(NXB, NBSPLIT);   // 64 x 16 = 1024 blocks, 4 blocks/CU
    chamfer_mfma<<<grid, BLOCK, 0, stream>>>(Ap, Bp, dmin_row, colpart);

    merge_kernel<<<NPTS / 256, 256, 0, stream>>>(colpart, dmin_row, part);
    final_kernel<<<1, 64, 0, stream>>>(part, out);
}